// Round 15
// baseline (312.326 us; speedup 1.0000x reference)
//
#include <hip/hip_runtime.h>

#define NTX   50000
#define NADDR 50000
#define NE    500000
#define GG    512
#define NEG   0.2f
#define MBLK  64
#define PBM   782    // ceil(50000/64)
#define NCHUNK 196   // ceil(50000/256)
#define GBLK  3125   // NTX/16 dst-blocks per edge type
#define RNG   2048   // dst range width per CSR-build block
#define NRANGE 25    // ceil(50000/2048)

typedef _Float16 f16;
typedef f16 f16x4 __attribute__((ext_vector_type(4)));
typedef f16 f16x8 __attribute__((ext_vector_type(8)));
typedef float f32x2 __attribute__((ext_vector_type(2)));
typedef float f32x4 __attribute__((ext_vector_type(4)));

__device__ __forceinline__ float lrelu(float x) { return x > 0.f ? x : NEG * x; }

// ---------------------------------------------------------------------------
// prep: fp16-transpose the three 128x128 weight matrices ONCE.
// ---------------------------------------------------------------------------
__global__ __launch_bounds__(256) void prep_kernel(
    const float* __restrict__ W_tx, const float* __restrict__ W_ad,
    const float* __restrict__ Wk,
    f16* __restrict__ Wt_tx, f16* __restrict__ Wt_ad, f16* __restrict__ Wkt)
{
    const float* W = (blockIdx.y == 0) ? W_tx : (blockIdx.y == 1) ? W_ad : Wk;
    f16* Wt        = (blockIdx.y == 0) ? Wt_tx : (blockIdx.y == 1) ? Wt_ad : Wkt;
    __shared__ f16 tile[32][136];
    const int t = threadIdx.x;
    const int j0 = blockIdx.x * 32;
    for (int i = t; i < 32 * 128; i += 256) {
        int r = i >> 7, c = i & 127;
        tile[r][c] = (f16)W[(size_t)(j0 + r) * 128 + c];
    }
    __syncthreads();
    for (int i = t; i < 128 * 8; i += 256) {
        int c = i >> 3, q = i & 7;
        f16x4 p = { tile[q * 4 + 0][c], tile[q * 4 + 1][c],
                    tile[q * 4 + 2][c], tile[q * 4 + 3][c] };
        *(f16x4*)&Wt[(size_t)c * 128 + j0 + q * 4] = p;
    }
}

// ---------------------------------------------------------------------------
// proj2 (MFMA): h = fp16(x @ W + b), fused attention-logit dots (fp32).
// ---------------------------------------------------------------------------
__global__ __launch_bounds__(256) void proj2_kernel(
    const float* __restrict__ x_tx, const f16* __restrict__ Wt_txg,
    const float* __restrict__ b_tx, f16* __restrict__ h_tx,
    const float* __restrict__ x_ad, const f16* __restrict__ Wt_adg,
    const float* __restrict__ b_ad, f16* __restrict__ h_ad,
    const float* __restrict__ a_dat, float* __restrict__ al_dat,
    const float* __restrict__ a_stt, float* __restrict__ al_stt,
    const float* __restrict__ a_dtt, float* __restrict__ al_dtt,
    const float* __restrict__ a_sat, float* __restrict__ al_sat)
{
    __shared__ f16 Wt[128][136];   // padded: 272 B row stride (16B-aligned)
    __shared__ f16 xt[MBLK][136];
    const bool is_tx = blockIdx.x < PBM;
    const float* x  = is_tx ? x_tx : x_ad;
    const f16* Wtg  = is_tx ? Wt_txg : Wt_adg;
    const float* b  = is_tx ? b_tx : b_ad;
    f16* h          = is_tx ? h_tx : h_ad;
    const int row0 = (is_tx ? blockIdx.x : blockIdx.x - PBM) * MBLK;
    const int t = threadIdx.x;

    {
        const f16x8* G = (const f16x8*)Wtg;
        for (int i = t; i < 128 * 16; i += 256) {
            int r = i >> 4, q = i & 15;
            *(f16x8*)&Wt[r][q * 8] = G[i];
        }
    }
    for (int i = t; i < MBLK * 32; i += 256) {
        int r = i >> 5, q = i & 31;
        int gr = row0 + r; if (gr >= NTX) gr = NTX - 1;
        float4 v = ((const float4*)x)[(size_t)gr * 32 + q];
        f16x4 p = {(f16)v.x, (f16)v.y, (f16)v.z, (f16)v.w};
        *(f16x4*)&xt[r][q * 4] = p;
    }
    __syncthreads();

    const int l = t & 63, w = t >> 6;
    const int l15 = l & 15, lq = l >> 4;

    f16x8 afrag[4];
#pragma unroll
    for (int kt = 0; kt < 4; kt++)
        afrag[kt] = *(const f16x8*)&xt[w * 16 + l15][kt * 32 + lq * 8];

    f32x4 acc[8];
#pragma unroll
    for (int n = 0; n < 8; n++) {
        float bc = b[n * 16 + l15];
        acc[n] = (f32x4){bc, bc, bc, bc};
#pragma unroll
        for (int kt = 0; kt < 4; kt++) {
            f16x8 bfrag = *(const f16x8*)&Wt[n * 16 + l15][kt * 32 + lq * 8];
            acc[n] = __builtin_amdgcn_mfma_f32_16x16x32_f16(afrag[kt], bfrag, acc[n], 0, 0, 0);
        }
    }

#pragma unroll
    for (int r = 0; r < 4; r++) {
        int row = row0 + w * 16 + lq * 4 + r;
        if (row < NTX) {
#pragma unroll
            for (int n = 0; n < 8; n++)
                h[(size_t)row * 128 + n * 16 + l15] = (f16)acc[n][r];
        }
    }

    auto do_dot = [&](const float* __restrict__ a, float* __restrict__ al) {
        float av[8];
#pragma unroll
        for (int n = 0; n < 8; n++) av[n] = a[n * 16 + l15];
#pragma unroll
        for (int r = 0; r < 4; r++) {
            float p0 = acc[0][r] * av[0] + acc[1][r] * av[1];
            float p1 = acc[2][r] * av[2] + acc[3][r] * av[3];
            float p2 = acc[4][r] * av[4] + acc[5][r] * av[5];
            float p3 = acc[6][r] * av[6] + acc[7][r] * av[7];
#pragma unroll
            for (int o = 1; o < 16; o <<= 1) {
                p0 += __shfl_xor(p0, o); p1 += __shfl_xor(p1, o);
                p2 += __shfl_xor(p2, o); p3 += __shfl_xor(p3, o);
            }
            int row = row0 + w * 16 + lq * 4 + r;
            if (l15 == 0 && row < NTX) {
                float4 v = make_float4(p0, p1, p2, p3);
                *(float4*)&al[(size_t)row * 4] = v;
            }
        }
    };
    if (is_tx) { do_dot(a_dat, al_dat); do_dot(a_stt, al_stt); do_dot(a_dtt, al_dtt); }
    else       { do_dot(a_sat, al_sat); }
}

// ---------------------------------------------------------------------------
// CSR build (NO global atomics):
//   rangedeg: per dst-range LDS histogram over streamed dst array -> deg
//   chunksum/chunkscan/scanwrite: exclusive scan -> row
//   rangefill: LDS cursors from row; csr[pos]=src (block-exclusive segment)
// ---------------------------------------------------------------------------
__global__ __launch_bounds__(1024) void rangedeg_kernel(
    const int* __restrict__ ei0, const int* __restrict__ ei1,
    int* __restrict__ deg0, int* __restrict__ deg1)
{
    const int* ei = blockIdx.y == 0 ? ei0 : ei1;
    int* deg      = blockIdx.y == 0 ? deg0 : deg1;
    __shared__ int hist[RNG];
    const int t = threadIdx.x;
    const int r0 = blockIdx.x * RNG;
    for (int j = t; j < RNG; j += 1024) hist[j] = 0;
    __syncthreads();
    const int4* dst4 = (const int4*)(ei + NE);
    for (int i = t; i < NE / 4; i += 1024) {
        int4 d4 = dst4[i];
        int a;
        a = d4.x - r0; if ((unsigned)a < RNG) atomicAdd(&hist[a], 1);
        a = d4.y - r0; if ((unsigned)a < RNG) atomicAdd(&hist[a], 1);
        a = d4.z - r0; if ((unsigned)a < RNG) atomicAdd(&hist[a], 1);
        a = d4.w - r0; if ((unsigned)a < RNG) atomicAdd(&hist[a], 1);
    }
    __syncthreads();
    for (int j = t; j < RNG; j += 1024) {
        int d = r0 + j;
        if (d < NTX) deg[d] = hist[j];
    }
}

__global__ __launch_bounds__(256) void chunksum_kernel(
    const int* __restrict__ deg0, const int* __restrict__ deg1,
    int* __restrict__ csum)   // [2][NCHUNK]
{
    const int* deg = blockIdx.y == 0 ? deg0 : deg1;
    __shared__ int s[256];
    const int t = threadIdx.x;
    int idx = blockIdx.x * 256 + t;
    s[t] = idx < NTX ? deg[idx] : 0;
    __syncthreads();
    for (int o = 128; o > 0; o >>= 1) {
        if (t < o) s[t] += s[t + o];
        __syncthreads();
    }
    if (t == 0) csum[blockIdx.y * NCHUNK + blockIdx.x] = s[0];
}

__global__ __launch_bounds__(256) void chunkscan_kernel(int* __restrict__ csum)
{
    __shared__ int s[256];
    const int t = threadIdx.x;
    int* base = csum + blockIdx.x * NCHUNK;
    int v = t < NCHUNK ? base[t] : 0;
    s[t] = v;
    __syncthreads();
    for (int o = 1; o < 256; o <<= 1) {
        int u = (t >= o) ? s[t - o] : 0;
        __syncthreads();
        s[t] += u;
        __syncthreads();
    }
    if (t < NCHUNK) base[t] = s[t] - v;   // exclusive
}

__global__ __launch_bounds__(256) void scanwrite_kernel(
    const int* __restrict__ deg0, const int* __restrict__ deg1,
    const int* __restrict__ csum,
    int* __restrict__ row0, int* __restrict__ row1)
{
    const int* deg = blockIdx.y == 0 ? deg0 : deg1;
    int* row       = blockIdx.y == 0 ? row0 : row1;
    __shared__ int s[256];
    const int t = threadIdx.x;
    int idx = blockIdx.x * 256 + t;
    int v = idx < NTX ? deg[idx] : 0;
    s[t] = v;
    __syncthreads();
    for (int o = 1; o < 256; o <<= 1) {
        int u = (t >= o) ? s[t - o] : 0;
        __syncthreads();
        s[t] += u;
        __syncthreads();
    }
    if (idx < NTX)
        row[idx] = s[t] - v + csum[blockIdx.y * NCHUNK + blockIdx.x];
}

__global__ __launch_bounds__(1024) void rangefill_kernel(
    const int* __restrict__ ei0, const int* __restrict__ row0, int* __restrict__ csr0,
    const int* __restrict__ ei1, const int* __restrict__ row1, int* __restrict__ csr1)
{
    const int* ei  = blockIdx.y == 0 ? ei0 : ei1;
    const int* row = blockIdx.y == 0 ? row0 : row1;
    int* csr       = blockIdx.y == 0 ? csr0 : csr1;
    __shared__ int cur[RNG];
    const int t = threadIdx.x;
    const int r0 = blockIdx.x * RNG;
    for (int j = t; j < RNG; j += 1024) {
        int d = r0 + j;
        cur[j] = (d < NTX) ? row[d] : 0;
    }
    __syncthreads();
    const int4* src4 = (const int4*)ei;
    const int4* dst4 = (const int4*)(ei + NE);
    for (int i = t; i < NE / 4; i += 1024) {
        int4 d4 = dst4[i];
        int4 s4 = src4[i];
        int a;
        a = d4.x - r0; if ((unsigned)a < RNG) { int p = atomicAdd(&cur[a], 1); csr[p] = s4.x; }
        a = d4.y - r0; if ((unsigned)a < RNG) { int p = atomicAdd(&cur[a], 1); csr[p] = s4.y; }
        a = d4.z - r0; if ((unsigned)a < RNG) { int p = atomicAdd(&cur[a], 1); csr[p] = s4.z; }
        a = d4.w - r0; if ((unsigned)a < RNG) { int p = atomicAdd(&cur[a], 1); csr[p] = s4.w; }
    }
}

// ---------------------------------------------------------------------------
// Gather GAT: 16 lanes per dst (f16x8/lane = 256B row per group), 4 dsts/wave,
// 16 dsts per 256-thr block. Flat 1D grid; edge type chosen by (bid&4) so
// XCDs 0-3 stream h_ad and XCDs 4-7 stream h_tx. 4-edge unroll; f32x2 acc.
// ---------------------------------------------------------------------------
__global__ __launch_bounds__(256) void gat_gather2_kernel(
    const int* __restrict__ row_at, const int* __restrict__ deg_at,
    const int* __restrict__ csr_at, const float* __restrict__ als_at,
    const float* __restrict__ ald_at, const f16* __restrict__ h_at,
    f16* __restrict__ out_at,
    const int* __restrict__ row_tt, const int* __restrict__ deg_tt,
    const int* __restrict__ csr_tt, const float* __restrict__ als_tt,
    const float* __restrict__ ald_tt, const f16* __restrict__ h_tt,
    f16* __restrict__ out_tt)
{
    const int bid = blockIdx.x;
    const bool at = ((bid & 4) == 0);
    const int dblk = (bid >> 3) * 4 + (bid & 3);
    if (dblk >= GBLK) return;

    const int* rs = at ? row_at : row_tt;
    const int* dg = at ? deg_at : deg_tt;
    const int* cs = at ? csr_at : csr_tt;
    const float* als = at ? als_at : als_tt;
    const float* ald = at ? ald_at : ald_tt;
    const f16* hsrc = at ? h_at : h_tt;
    f16* out = at ? out_at : out_tt;

    const int t = threadIdx.x;
    const int d = dblk * 16 + (t >> 4);         // uniform per 16-lane group
    const int ln8 = t & 15;                     // chunk: channels [ln8*8, ln8*8+8)
    const int head = ln8 >> 2;
    const int beg = rs[d];
    const int n = dg[d];
    const float aldv = ald[d * 4 + head];
    const f16x8* H = (const f16x8*)hsrc;

    f32x2 acc[4] = {{0.f, 0.f}, {0.f, 0.f}, {0.f, 0.f}, {0.f, 0.f}};
    float den = 0.f;
    int i = 0;
    for (; i + 4 <= n; i += 4) {
        int s0 = cs[beg + i],     s1 = cs[beg + i + 1];
        int s2 = cs[beg + i + 2], s3 = cs[beg + i + 3];
        float l0 = als[s0 * 4 + head], l1 = als[s1 * 4 + head];
        float l2 = als[s2 * 4 + head], l3 = als[s3 * 4 + head];
        f16x8 h0 = H[(size_t)s0 * 16 + ln8];
        f16x8 h1 = H[(size_t)s1 * 16 + ln8];
        f16x8 h2 = H[(size_t)s2 * 16 + ln8];
        f16x8 h3 = H[(size_t)s3 * 16 + ln8];
        float w0 = __expf(lrelu(l0 + aldv));
        float w1 = __expf(lrelu(l1 + aldv));
        float w2 = __expf(lrelu(l2 + aldv));
        float w3 = __expf(lrelu(l3 + aldv));
        den += (w0 + w1) + (w2 + w3);
#pragma unroll
        for (int q = 0; q < 4; q++) {
            f32x2 a0 = {(float)h0[2 * q], (float)h0[2 * q + 1]};
            f32x2 a1 = {(float)h1[2 * q], (float)h1[2 * q + 1]};
            f32x2 a2 = {(float)h2[2 * q], (float)h2[2 * q + 1]};
            f32x2 a3 = {(float)h3[2 * q], (float)h3[2 * q + 1]};
            acc[q] = a0 * w0 + (a1 * w1 + (a2 * w2 + (a3 * w3 + acc[q])));
        }
    }
    for (; i < n; i++) {
        int s0 = cs[beg + i];
        float l0 = als[s0 * 4 + head];
        f16x8 h0 = H[(size_t)s0 * 16 + ln8];
        float w0 = __expf(lrelu(l0 + aldv));
        den += w0;
#pragma unroll
        for (int q = 0; q < 4; q++) {
            f32x2 a0 = {(float)h0[2 * q], (float)h0[2 * q + 1]};
            acc[q] = a0 * w0 + acc[q];
        }
    }
    float inv = 1.f / (den + 1e-16f);
    f16x8 o;
#pragma unroll
    for (int q = 0; q < 4; q++) {
        float v0 = acc[q][0] * inv, v1 = acc[q][1] * inv;
        o[2 * q]     = (f16)(v0 > 0.f ? v0 : 0.f);
        o[2 * q + 1] = (f16)(v1 > 0.f ? v1 : 0.f);
    }
    ((f16x8*)out)[(size_t)d * 16 + ln8] = o;
}

// ---------------------------------------------------------------------------
// tanh GEMM (MFMA): BOTH metapaths per block -- Wk^T staged once (pre-transposed).
// ---------------------------------------------------------------------------
__global__ __launch_bounds__(256) void tanh_gemm_kernel(
    const f16* __restrict__ out_at, const f16* __restrict__ out_tt,
    const f16* __restrict__ Wktg, const float* __restrict__ bk,
    float* __restrict__ part)    // [2][PBM][128]
{
    __shared__ f16 Wt[128][136];
    __shared__ f16 xt[MBLK][136];
    const int row0 = blockIdx.x * MBLK;
    const int t = threadIdx.x;

    {
        const f16x8* G = (const f16x8*)Wktg;
        for (int i = t; i < 128 * 16; i += 256) {
            int r = i >> 4, q = i & 15;
            *(f16x8*)&Wt[r][q * 8] = G[i];
        }
    }

    const int l = t & 63, w = t >> 6;
    const int l15 = l & 15, lq = l >> 4;

    for (int y = 0; y < 2; y++) {
        const f16* src = (y == 0) ? out_at : out_tt;
        __syncthreads();   // y=0: nothing yet; y=1: Sblk reads done
        for (int i = t; i < MBLK * 16; i += 256) {
            int r = i >> 4, q = i & 15;
            int gr = row0 + r; if (gr >= NTX) gr = NTX - 1;
            *(f16x8*)&xt[r][q * 8] = ((const f16x8*)src)[(size_t)gr * 16 + q];
        }
        __syncthreads();   // xt (and Wt, first pass) staged

        f16x8 afrag[4];
#pragma unroll
        for (int kt = 0; kt < 4; kt++)
            afrag[kt] = *(const f16x8*)&xt[w * 16 + l15][kt * 32 + lq * 8];

        float pn[8];
#pragma unroll
        for (int n = 0; n < 8; n++) {
            float bc = bk[n * 16 + l15];
            f32x4 acc = (f32x4){bc, bc, bc, bc};
#pragma unroll
            for (int kt = 0; kt < 4; kt++) {
                f16x8 bfrag = *(const f16x8*)&Wt[n * 16 + l15][kt * 32 + lq * 8];
                acc = __builtin_amdgcn_mfma_f32_16x16x32_f16(afrag[kt], bfrag, acc, 0, 0, 0);
            }
            float s = 0.f;
#pragma unroll
            for (int r = 0; r < 4; r++) {
                int row = row0 + w * 16 + lq * 4 + r;
                if (row < NTX) s += tanhf(acc[r]);
            }
            s += __shfl_xor(s, 16);
            s += __shfl_xor(s, 32);
            pn[n] = s;
        }

        __syncthreads();                  // all waves done reading xt
        float* Sblk = (float*)&xt[0][0];  // reuse xt as [4][128] float
        if (l < 16) {
#pragma unroll
            for (int n = 0; n < 8; n++)
                Sblk[w * 128 + n * 16 + l15] = pn[n];
        }
        __syncthreads();
        if (t < 128)
            part[((size_t)y * PBM + blockIdx.x) * 128 + t] =
                Sblk[t] + Sblk[128 + t] + Sblk[256 + t] + Sblk[384 + t];
    }
}

// ---------------------------------------------------------------------------
// reduce partials -> S_k[c]
// ---------------------------------------------------------------------------
__global__ __launch_bounds__(128) void reduceS_kernel(
    const float* __restrict__ part, float* __restrict__ S_at, float* __restrict__ S_tt)
{
    const int k = blockIdx.y;
    const int c = threadIdx.x;
    float* S = (k == 0) ? S_at : S_tt;
    const int b0 = blockIdx.x * 25;
    const int b1 = min(b0 + 25, PBM);
    float s = 0.f;
    for (int b = b0; b < b1; b++)
        s += part[((size_t)k * PBM + b) * 128 + c];
    atomicAdd(&S[c], s);
}

// ---------------------------------------------------------------------------
// attn: score_k = (q . S_k) / NTX; attn = softmax over k=2
// ---------------------------------------------------------------------------
__global__ __launch_bounds__(128) void attn_kernel(
    const float* __restrict__ S0, const float* __restrict__ S1,
    const float* __restrict__ q, float* __restrict__ attn)
{
    __shared__ float r0[128], r1[128];
    int c = threadIdx.x;
    r0[c] = q[c] * S0[c];
    r1[c] = q[c] * S1[c];
    __syncthreads();
    for (int s = 64; s > 0; s >>= 1) {
        if (c < s) { r0[c] += r0[c + s]; r1[c] += r1[c + s]; }
        __syncthreads();
    }
    if (c == 0) {
        float s0 = r0[0] / (float)NTX, s1 = r1[0] / (float)NTX;
        float m = fmaxf(s0, s1);
        float e0 = expf(s0 - m), e1 = expf(s1 - m);
        float inv = 1.f / (e0 + e1);
        attn[0] = e0 * inv;
        attn[1] = e1 * inv;
    }
}

// ---------------------------------------------------------------------------
// final_pool: batch is SORTED -> group g is a contiguous run [lo,hi).
// 1024 threads = 8 row-slices x 128 channels; LDS tree over slices,
// then fused 128->2 linear.
// ---------------------------------------------------------------------------
__device__ __forceinline__ int lower_bound_g(const int* __restrict__ batch, int val)
{
    int lo = 0, hi = NTX;
    while (lo < hi) {
        int mid = (lo + hi) >> 1;
        if (batch[mid] < val) lo = mid + 1; else hi = mid;
    }
    return lo;
}

__global__ __launch_bounds__(1024) void final_pool_kernel(
    const f16* __restrict__ out_at, const f16* __restrict__ out_tt,
    const int* __restrict__ batch, const float* __restrict__ attn,
    const float* __restrict__ Wl, const float* __restrict__ bl,
    float* __restrict__ out)
{
    __shared__ float r0s[8][128], r1s[8][128];
    const int g = blockIdx.x;
    const int t = threadIdx.x;
    const int sub = t >> 7, c = t & 127;
    const int lo = lower_bound_g(batch, g);
    const int hi = lower_bound_g(batch, g + 1);
    float s0 = 0.f, s1 = 0.f;
    for (int n = lo + sub; n < hi; n += 8) {
        s0 += (float)out_at[(size_t)n * 128 + c];
        s1 += (float)out_tt[(size_t)n * 128 + c];
    }
    r0s[sub][c] = s0;
    r1s[sub][c] = s1;
    __syncthreads();
    for (int o = 4; o > 0; o >>= 1) {
        if (sub < o) {
            r0s[sub][c] += r0s[sub + o][c];
            r1s[sub][c] += r1s[sub + o][c];
        }
        __syncthreads();
    }
    if (t < 128) {
        float pooled = (attn[0] * r0s[0][t] + attn[1] * r1s[0][t])
                     / fmaxf((float)(hi - lo), 1.f);
        r0s[1][t] = pooled * Wl[t * 2 + 0];
        r1s[1][t] = pooled * Wl[t * 2 + 1];
    }
    __syncthreads();
    for (int s = 64; s > 0; s >>= 1) {
        if (t < s) { r0s[1][t] += r0s[1][t + s]; r1s[1][t] += r1s[1][t + s]; }
        __syncthreads();
    }
    if (t == 0) {
        out[g * 2 + 0] = r0s[1][0] + bl[0];
        out[g * 2 + 1] = r1s[1][0] + bl[1];
    }
}

// ---------------------------------------------------------------------------
extern "C" void kernel_launch(void* const* d_in, const int* in_sizes, int n_in,
                              void* d_out, int out_size, void* d_ws, size_t ws_size,
                              hipStream_t stream)
{
    const float* x_tx     = (const float*)d_in[0];
    const float* x_ad     = (const float*)d_in[1];
    // d_in[2] = ei_ta (dead: out_ta never consumed)
    const int*   ei_at    = (const int*)d_in[3];
    const int*   ei_tt    = (const int*)d_in[4];
    const int*   batch    = (const int*)d_in[5];
    const float* W_tx     = (const float*)d_in[6];
    const float* b_tx     = (const float*)d_in[7];
    const float* W_ad     = (const float*)d_in[8];
    const float* b_ad     = (const float*)d_in[9];
    // d_in[10], d_in[11] = a_src_ta, a_dst_ta (dead)
    const float* a_src_at = (const float*)d_in[12];
    const float* a_dst_at = (const float*)d_in[13];
    const float* a_src_tt = (const float*)d_in[14];
    const float* a_dst_tt = (const float*)d_in[15];
    const float* Wk       = (const float*)d_in[16];
    const float* bk       = (const float*)d_in[17];
    const float* q        = (const float*)d_in[18];
    const float* Wl       = (const float*)d_in[19];
    const float* bl       = (const float*)d_in[20];
    float* out = (float*)d_out;

    char* ws = (char*)d_ws;
    size_t off = 0;
    auto alloc = [&](size_t bytes) -> void* {
        void* p = ws + off;
        off += (bytes + 255) & ~(size_t)255;
        return p;
    };
    f16* h_tx      = (f16*)alloc((size_t)NTX * 128 * 2);
    f16* h_ad      = (f16*)alloc((size_t)NADDR * 128 * 2);
    f16* Wt_txg    = (f16*)alloc((size_t)128 * 128 * 2);   // pre-transposed fp16 weights
    f16* Wt_adg    = (f16*)alloc((size_t)128 * 128 * 2);
    f16* Wktg      = (f16*)alloc((size_t)128 * 128 * 2);
    float* al_sat  = (float*)alloc((size_t)NADDR * 4 * 4);
    float* al_dat  = (float*)alloc((size_t)NTX * 4 * 4);
    float* al_stt  = (float*)alloc((size_t)NTX * 4 * 4);
    float* al_dtt  = (float*)alloc((size_t)NTX * 4 * 4);
    f16* out_at    = (f16*)alloc((size_t)NTX * 128 * 2);   // fully written by gather
    f16* out_tt    = (f16*)alloc((size_t)NTX * 128 * 2);
    int* csr_at    = (int*)alloc((size_t)NE * 4);
    int* csr_tt    = (int*)alloc((size_t)NE * 4);
    int* row_at    = (int*)alloc((size_t)NTX * 4);
    int* row_tt    = (int*)alloc((size_t)NTX * 4);
    int* deg_at    = (int*)alloc((size_t)NTX * 4);          // fully written by rangedeg
    int* deg_tt    = (int*)alloc((size_t)NTX * 4);
    int* csum      = (int*)alloc((size_t)2 * NCHUNK * 4);
    float* part    = (float*)alloc((size_t)2 * PBM * 128 * 4);
    // ---- zeroed region (S accumulators) ----
    char* zero0 = ws + off;
    float* S_at    = (float*)alloc(128 * 4);
    float* S_tt    = (float*)alloc(128 * 4);
    size_t zbytes = (size_t)((ws + off) - zero0);
    float* attnw   = (float*)alloc(2 * 4);

    hipMemsetAsync(zero0, 0, zbytes, stream);

    // one-shot fp16 weight transposes
    dim3 pgrid(4, 3);
    prep_kernel<<<pgrid, 256, 0, stream>>>(W_tx, W_ad, Wk, Wt_txg, Wt_adg, Wktg);

    // projections + attention-logit dots (MFMA, both node types, one dispatch)
    proj2_kernel<<<2 * PBM, 256, 0, stream>>>(
        x_tx, Wt_txg, b_tx, h_tx, x_ad, Wt_adg, b_ad, h_ad,
        a_dst_at, al_dat, a_src_tt, al_stt, a_dst_tt, al_dtt,
        a_src_at, al_sat);

    // CSR build (dst-major), range-partitioned, no global atomics
    dim3 rgrid2(NRANGE, 2);
    rangedeg_kernel<<<rgrid2, 1024, 0, stream>>>(ei_at, ei_tt, deg_at, deg_tt);
    dim3 sgrid(NCHUNK, 2);
    chunksum_kernel<<<sgrid, 256, 0, stream>>>(deg_at, deg_tt, csum);
    chunkscan_kernel<<<2, 256, 0, stream>>>(csum);
    scanwrite_kernel<<<sgrid, 256, 0, stream>>>(deg_at, deg_tt, csum, row_at, row_tt);
    rangefill_kernel<<<rgrid2, 1024, 0, stream>>>(ei_at, row_at, csr_at,
                                                  ei_tt, row_tt, csr_tt);

    // gather-style GAT: flat grid, 8-block tiles split types across XCD halves
    gat_gather2_kernel<<<PBM * 8, 256, 0, stream>>>(
        row_at, deg_at, csr_at, al_sat, al_dat, h_ad, out_at,
        row_tt, deg_tt, csr_tt, al_stt, al_dtt, h_tx, out_tt);

    // semantic attention: MFMA tanh GEMM (both metapaths/block) -> reduce -> softmax
    tanh_gemm_kernel<<<PBM, 256, 0, stream>>>(out_at, out_tt, Wktg, bk, part);
    dim3 rgrid(32, 2);
    reduceS_kernel<<<rgrid, 128, 0, stream>>>(part, S_at, S_tt);
    attn_kernel<<<1, 128, 0, stream>>>(S_at, S_tt, q, attnw);

    // fused pooling (sorted batch -> contiguous runs) + final linear
    final_pool_kernel<<<GG, 1024, 0, stream>>>(out_at, out_tt, batch, attnw, Wl, bl, out);
}

// Round 16
// 183.996 us; speedup vs baseline: 1.6975x; 1.6975x over previous
//
#include <hip/hip_runtime.h>

#define NTX   50000
#define NADDR 50000
#define NE    500000
#define GG    512
#define NEG   0.2f
#define MBLK  64
#define PBM   782    // ceil(50000/64)
#define NCHUNK 196   // ceil(50000/256)
#define GBLK  3125   // NTX/16 dst-blocks per edge type
#define EPB   640    // edges per proj2 block: 2*PBM*640 >= 2*NE

typedef _Float16 f16;
typedef f16 f16x4 __attribute__((ext_vector_type(4)));
typedef f16 f16x8 __attribute__((ext_vector_type(8)));
typedef float f32x2 __attribute__((ext_vector_type(2)));
typedef float f32x4 __attribute__((ext_vector_type(4)));

__device__ __forceinline__ float lrelu(float x) { return x > 0.f ? x : NEG * x; }

// ---------------------------------------------------------------------------
// prep: fp16-transpose the three 128x128 weight matrices ONCE.
// ---------------------------------------------------------------------------
__global__ __launch_bounds__(256) void prep_kernel(
    const float* __restrict__ W_tx, const float* __restrict__ W_ad,
    const float* __restrict__ Wk,
    f16* __restrict__ Wt_tx, f16* __restrict__ Wt_ad, f16* __restrict__ Wkt)
{
    const float* W = (blockIdx.y == 0) ? W_tx : (blockIdx.y == 1) ? W_ad : Wk;
    f16* Wt        = (blockIdx.y == 0) ? Wt_tx : (blockIdx.y == 1) ? Wt_ad : Wkt;
    __shared__ f16 tile[32][136];
    const int t = threadIdx.x;
    const int j0 = blockIdx.x * 32;
    for (int i = t; i < 32 * 128; i += 256) {
        int r = i >> 7, c = i & 127;
        tile[r][c] = (f16)W[(size_t)(j0 + r) * 128 + c];
    }
    __syncthreads();
    for (int i = t; i < 128 * 8; i += 256) {
        int c = i >> 3, q = i & 7;
        f16x4 p = { tile[q * 4 + 0][c], tile[q * 4 + 1][c],
                    tile[q * 4 + 2][c], tile[q * 4 + 3][c] };
        *(f16x4*)&Wt[(size_t)c * 128 + j0 + q * 4] = p;
    }
}

// ---------------------------------------------------------------------------
// proj2 (MFMA): h = fp16(x @ W + b), fused attention-logit dots (fp32),
// PLUS fused degree/rank atomics for the CSR build (each block owns EPB
// edges; the ~600cyc atomic round trips hide under other waves' MFMA).
// ---------------------------------------------------------------------------
__global__ __launch_bounds__(256) void proj2_kernel(
    const float* __restrict__ x_tx, const f16* __restrict__ Wt_txg,
    const float* __restrict__ b_tx, f16* __restrict__ h_tx,
    const float* __restrict__ x_ad, const f16* __restrict__ Wt_adg,
    const float* __restrict__ b_ad, f16* __restrict__ h_ad,
    const float* __restrict__ a_dat, float* __restrict__ al_dat,
    const float* __restrict__ a_stt, float* __restrict__ al_stt,
    const float* __restrict__ a_dtt, float* __restrict__ al_dtt,
    const float* __restrict__ a_sat, float* __restrict__ al_sat,
    const int* __restrict__ ei0, const int* __restrict__ ei1,
    int* __restrict__ deg0, int* __restrict__ deg1,
    int* __restrict__ rank0, int* __restrict__ rank1)
{
    __shared__ f16 Wt[128][136];   // padded: 272 B row stride (16B-aligned)
    __shared__ f16 xt[MBLK][136];
    const bool is_tx = blockIdx.x < PBM;
    const float* x  = is_tx ? x_tx : x_ad;
    const f16* Wtg  = is_tx ? Wt_txg : Wt_adg;
    const float* b  = is_tx ? b_tx : b_ad;
    f16* h          = is_tx ? h_tx : h_ad;
    const int row0 = (is_tx ? blockIdx.x : blockIdx.x - PBM) * MBLK;
    const int t = threadIdx.x;

    {
        const f16x8* G = (const f16x8*)Wtg;
        for (int i = t; i < 128 * 16; i += 256) {
            int r = i >> 4, q = i & 15;
            *(f16x8*)&Wt[r][q * 8] = G[i];
        }
    }
    for (int i = t; i < MBLK * 32; i += 256) {
        int r = i >> 5, q = i & 31;
        int gr = row0 + r; if (gr >= NTX) gr = NTX - 1;
        float4 v = ((const float4*)x)[(size_t)gr * 32 + q];
        f16x4 p = {(f16)v.x, (f16)v.y, (f16)v.z, (f16)v.w};
        *(f16x4*)&xt[r][q * 4] = p;
    }

    // fused CSR degree/rank atomics (independent of the GEMM)
    {
        const int e0 = blockIdx.x * EPB;
        const int e1 = min(e0 + EPB, 2 * NE);
        for (int e = e0 + t; e < e1; e += 256) {
            if (e < NE) {
                int d = ei0[NE + e];
                rank0[e] = atomicAdd(&deg0[d], 1);
            } else {
                int ee = e - NE;
                int d = ei1[NE + ee];
                rank1[ee] = atomicAdd(&deg1[d], 1);
            }
        }
    }
    __syncthreads();

    const int l = t & 63, w = t >> 6;
    const int l15 = l & 15, lq = l >> 4;

    f16x8 afrag[4];
#pragma unroll
    for (int kt = 0; kt < 4; kt++)
        afrag[kt] = *(const f16x8*)&xt[w * 16 + l15][kt * 32 + lq * 8];

    f32x4 acc[8];
#pragma unroll
    for (int n = 0; n < 8; n++) {
        float bc = b[n * 16 + l15];
        acc[n] = (f32x4){bc, bc, bc, bc};
#pragma unroll
        for (int kt = 0; kt < 4; kt++) {
            f16x8 bfrag = *(const f16x8*)&Wt[n * 16 + l15][kt * 32 + lq * 8];
            acc[n] = __builtin_amdgcn_mfma_f32_16x16x32_f16(afrag[kt], bfrag, acc[n], 0, 0, 0);
        }
    }

#pragma unroll
    for (int r = 0; r < 4; r++) {
        int row = row0 + w * 16 + lq * 4 + r;
        if (row < NTX) {
#pragma unroll
            for (int n = 0; n < 8; n++)
                h[(size_t)row * 128 + n * 16 + l15] = (f16)acc[n][r];
        }
    }

    auto do_dot = [&](const float* __restrict__ a, float* __restrict__ al) {
        float av[8];
#pragma unroll
        for (int n = 0; n < 8; n++) av[n] = a[n * 16 + l15];
#pragma unroll
        for (int r = 0; r < 4; r++) {
            float p0 = acc[0][r] * av[0] + acc[1][r] * av[1];
            float p1 = acc[2][r] * av[2] + acc[3][r] * av[3];
            float p2 = acc[4][r] * av[4] + acc[5][r] * av[5];
            float p3 = acc[6][r] * av[6] + acc[7][r] * av[7];
#pragma unroll
            for (int o = 1; o < 16; o <<= 1) {
                p0 += __shfl_xor(p0, o); p1 += __shfl_xor(p1, o);
                p2 += __shfl_xor(p2, o); p3 += __shfl_xor(p3, o);
            }
            int row = row0 + w * 16 + lq * 4 + r;
            if (l15 == 0 && row < NTX) {
                float4 v = make_float4(p0, p1, p2, p3);
                *(float4*)&al[(size_t)row * 4] = v;
            }
        }
    };
    if (is_tx) { do_dot(a_dat, al_dat); do_dot(a_stt, al_stt); do_dot(a_dtt, al_dtt); }
    else       { do_dot(a_sat, al_sat); }
}

// ---------------------------------------------------------------------------
// CSR build rest: chunksum -> chunkscan -> scanwrite -> fill (no atomics)
// ---------------------------------------------------------------------------
__global__ __launch_bounds__(256) void chunksum_kernel(
    const int* __restrict__ deg0, const int* __restrict__ deg1,
    int* __restrict__ csum)   // [2][NCHUNK]
{
    const int* deg = blockIdx.y == 0 ? deg0 : deg1;
    __shared__ int s[256];
    const int t = threadIdx.x;
    int idx = blockIdx.x * 256 + t;
    s[t] = idx < NTX ? deg[idx] : 0;
    __syncthreads();
    for (int o = 128; o > 0; o >>= 1) {
        if (t < o) s[t] += s[t + o];
        __syncthreads();
    }
    if (t == 0) csum[blockIdx.y * NCHUNK + blockIdx.x] = s[0];
}

__global__ __launch_bounds__(256) void chunkscan_kernel(int* __restrict__ csum)
{
    __shared__ int s[256];
    const int t = threadIdx.x;
    int* base = csum + blockIdx.x * NCHUNK;
    int v = t < NCHUNK ? base[t] : 0;
    s[t] = v;
    __syncthreads();
    for (int o = 1; o < 256; o <<= 1) {
        int u = (t >= o) ? s[t - o] : 0;
        __syncthreads();
        s[t] += u;
        __syncthreads();
    }
    if (t < NCHUNK) base[t] = s[t] - v;   // exclusive
}

__global__ __launch_bounds__(256) void scanwrite_kernel(
    const int* __restrict__ deg0, const int* __restrict__ deg1,
    const int* __restrict__ csum,
    int* __restrict__ row0, int* __restrict__ row1)
{
    const int* deg = blockIdx.y == 0 ? deg0 : deg1;
    int* row       = blockIdx.y == 0 ? row0 : row1;
    __shared__ int s[256];
    const int t = threadIdx.x;
    int idx = blockIdx.x * 256 + t;
    int v = idx < NTX ? deg[idx] : 0;
    s[t] = v;
    __syncthreads();
    for (int o = 1; o < 256; o <<= 1) {
        int u = (t >= o) ? s[t - o] : 0;
        __syncthreads();
        s[t] += u;
        __syncthreads();
    }
    if (idx < NTX)
        row[idx] = s[t] - v + csum[blockIdx.y * NCHUNK + blockIdx.x];
}

// fill: NO atomics. pos = row[dst] + rank[e]; one scattered 4B store.
__global__ __launch_bounds__(256) void fill2_kernel(
    const int* __restrict__ ei0, const int* __restrict__ rank0,
    const int* __restrict__ row0, int* __restrict__ csr0,
    const int* __restrict__ ei1, const int* __restrict__ rank1,
    const int* __restrict__ row1, int* __restrict__ csr1)
{
    int idx = blockIdx.x * 256 + threadIdx.x;
    const int* ei; const int* rank; const int* row; int* csr;
    int e;
    if (idx < NE)          { ei = ei0; rank = rank0; row = row0; csr = csr0; e = idx; }
    else if (idx < 2 * NE) { ei = ei1; rank = rank1; row = row1; csr = csr1; e = idx - NE; }
    else return;
    int s = ei[e];
    int d = ei[NE + e];
    csr[row[d] + rank[e]] = s;
}

// ---------------------------------------------------------------------------
// Gather GAT: 16 lanes per dst (f16x8/lane = 256B row per group), 4 dsts/wave,
// 16 dsts per 256-thr block. Flat 1D grid; edge type chosen by (bid&4) so
// XCDs 0-3 stream h_ad and XCDs 4-7 stream h_tx. 4-edge unroll; f32x2 acc.
// ---------------------------------------------------------------------------
__global__ __launch_bounds__(256) void gat_gather2_kernel(
    const int* __restrict__ row_at, const int* __restrict__ deg_at,
    const int* __restrict__ csr_at, const float* __restrict__ als_at,
    const float* __restrict__ ald_at, const f16* __restrict__ h_at,
    f16* __restrict__ out_at,
    const int* __restrict__ row_tt, const int* __restrict__ deg_tt,
    const int* __restrict__ csr_tt, const float* __restrict__ als_tt,
    const float* __restrict__ ald_tt, const f16* __restrict__ h_tt,
    f16* __restrict__ out_tt)
{
    const int bid = blockIdx.x;
    const bool at = ((bid & 4) == 0);
    const int dblk = (bid >> 3) * 4 + (bid & 3);
    if (dblk >= GBLK) return;

    const int* rs = at ? row_at : row_tt;
    const int* dg = at ? deg_at : deg_tt;
    const int* cs = at ? csr_at : csr_tt;
    const float* als = at ? als_at : als_tt;
    const float* ald = at ? ald_at : ald_tt;
    const f16* hsrc = at ? h_at : h_tt;
    f16* out = at ? out_at : out_tt;

    const int t = threadIdx.x;
    const int d = dblk * 16 + (t >> 4);         // uniform per 16-lane group
    const int ln8 = t & 15;                     // chunk: channels [ln8*8, ln8*8+8)
    const int head = ln8 >> 2;
    const int beg = rs[d];
    const int n = dg[d];
    const float aldv = ald[d * 4 + head];
    const f16x8* H = (const f16x8*)hsrc;

    f32x2 acc[4] = {{0.f, 0.f}, {0.f, 0.f}, {0.f, 0.f}, {0.f, 0.f}};
    float den = 0.f;
    int i = 0;
    for (; i + 4 <= n; i += 4) {
        int s0 = cs[beg + i],     s1 = cs[beg + i + 1];
        int s2 = cs[beg + i + 2], s3 = cs[beg + i + 3];
        float l0 = als[s0 * 4 + head], l1 = als[s1 * 4 + head];
        float l2 = als[s2 * 4 + head], l3 = als[s3 * 4 + head];
        f16x8 h0 = H[(size_t)s0 * 16 + ln8];
        f16x8 h1 = H[(size_t)s1 * 16 + ln8];
        f16x8 h2 = H[(size_t)s2 * 16 + ln8];
        f16x8 h3 = H[(size_t)s3 * 16 + ln8];
        float w0 = __expf(lrelu(l0 + aldv));
        float w1 = __expf(lrelu(l1 + aldv));
        float w2 = __expf(lrelu(l2 + aldv));
        float w3 = __expf(lrelu(l3 + aldv));
        den += (w0 + w1) + (w2 + w3);
#pragma unroll
        for (int q = 0; q < 4; q++) {
            f32x2 a0 = {(float)h0[2 * q], (float)h0[2 * q + 1]};
            f32x2 a1 = {(float)h1[2 * q], (float)h1[2 * q + 1]};
            f32x2 a2 = {(float)h2[2 * q], (float)h2[2 * q + 1]};
            f32x2 a3 = {(float)h3[2 * q], (float)h3[2 * q + 1]};
            acc[q] = a0 * w0 + (a1 * w1 + (a2 * w2 + (a3 * w3 + acc[q])));
        }
    }
    for (; i < n; i++) {
        int s0 = cs[beg + i];
        float l0 = als[s0 * 4 + head];
        f16x8 h0 = H[(size_t)s0 * 16 + ln8];
        float w0 = __expf(lrelu(l0 + aldv));
        den += w0;
#pragma unroll
        for (int q = 0; q < 4; q++) {
            f32x2 a0 = {(float)h0[2 * q], (float)h0[2 * q + 1]};
            acc[q] = a0 * w0 + acc[q];
        }
    }
    float inv = 1.f / (den + 1e-16f);
    f16x8 o;
#pragma unroll
    for (int q = 0; q < 4; q++) {
        float v0 = acc[q][0] * inv, v1 = acc[q][1] * inv;
        o[2 * q]     = (f16)(v0 > 0.f ? v0 : 0.f);
        o[2 * q + 1] = (f16)(v1 > 0.f ? v1 : 0.f);
    }
    ((f16x8*)out)[(size_t)d * 16 + ln8] = o;
}

// ---------------------------------------------------------------------------
// tanh GEMM (MFMA): BOTH metapaths per block -- Wk^T staged once (pre-transposed).
// ---------------------------------------------------------------------------
__global__ __launch_bounds__(256) void tanh_gemm_kernel(
    const f16* __restrict__ out_at, const f16* __restrict__ out_tt,
    const f16* __restrict__ Wktg, const float* __restrict__ bk,
    float* __restrict__ part)    // [2][PBM][128]
{
    __shared__ f16 Wt[128][136];
    __shared__ f16 xt[MBLK][136];
    const int row0 = blockIdx.x * MBLK;
    const int t = threadIdx.x;

    {
        const f16x8* G = (const f16x8*)Wktg;
        for (int i = t; i < 128 * 16; i += 256) {
            int r = i >> 4, q = i & 15;
            *(f16x8*)&Wt[r][q * 8] = G[i];
        }
    }

    const int l = t & 63, w = t >> 6;
    const int l15 = l & 15, lq = l >> 4;

    for (int y = 0; y < 2; y++) {
        const f16* src = (y == 0) ? out_at : out_tt;
        __syncthreads();   // y=0: nothing yet; y=1: Sblk reads done
        for (int i = t; i < MBLK * 16; i += 256) {
            int r = i >> 4, q = i & 15;
            int gr = row0 + r; if (gr >= NTX) gr = NTX - 1;
            *(f16x8*)&xt[r][q * 8] = ((const f16x8*)src)[(size_t)gr * 16 + q];
        }
        __syncthreads();   // xt (and Wt, first pass) staged

        f16x8 afrag[4];
#pragma unroll
        for (int kt = 0; kt < 4; kt++)
            afrag[kt] = *(const f16x8*)&xt[w * 16 + l15][kt * 32 + lq * 8];

        float pn[8];
#pragma unroll
        for (int n = 0; n < 8; n++) {
            float bc = bk[n * 16 + l15];
            f32x4 acc = (f32x4){bc, bc, bc, bc};
#pragma unroll
            for (int kt = 0; kt < 4; kt++) {
                f16x8 bfrag = *(const f16x8*)&Wt[n * 16 + l15][kt * 32 + lq * 8];
                acc = __builtin_amdgcn_mfma_f32_16x16x32_f16(afrag[kt], bfrag, acc, 0, 0, 0);
            }
            float s = 0.f;
#pragma unroll
            for (int r = 0; r < 4; r++) {
                int row = row0 + w * 16 + lq * 4 + r;
                if (row < NTX) s += tanhf(acc[r]);
            }
            s += __shfl_xor(s, 16);
            s += __shfl_xor(s, 32);
            pn[n] = s;
        }

        __syncthreads();                  // all waves done reading xt
        float* Sblk = (float*)&xt[0][0];  // reuse xt as [4][128] float
        if (l < 16) {
#pragma unroll
            for (int n = 0; n < 8; n++)
                Sblk[w * 128 + n * 16 + l15] = pn[n];
        }
        __syncthreads();
        if (t < 128)
            part[((size_t)y * PBM + blockIdx.x) * 128 + t] =
                Sblk[t] + Sblk[128 + t] + Sblk[256 + t] + Sblk[384 + t];
    }
}

// ---------------------------------------------------------------------------
// reduce partials -> S_k[c]
// ---------------------------------------------------------------------------
__global__ __launch_bounds__(128) void reduceS_kernel(
    const float* __restrict__ part, float* __restrict__ S_at, float* __restrict__ S_tt)
{
    const int k = blockIdx.y;
    const int c = threadIdx.x;
    float* S = (k == 0) ? S_at : S_tt;
    const int b0 = blockIdx.x * 25;
    const int b1 = min(b0 + 25, PBM);
    float s = 0.f;
    for (int b = b0; b < b1; b++)
        s += part[((size_t)k * PBM + b) * 128 + c];
    atomicAdd(&S[c], s);
}

// ---------------------------------------------------------------------------
// attn: score_k = (q . S_k) / NTX; attn = softmax over k=2
// ---------------------------------------------------------------------------
__global__ __launch_bounds__(128) void attn_kernel(
    const float* __restrict__ S0, const float* __restrict__ S1,
    const float* __restrict__ q, float* __restrict__ attn)
{
    __shared__ float r0[128], r1[128];
    int c = threadIdx.x;
    r0[c] = q[c] * S0[c];
    r1[c] = q[c] * S1[c];
    __syncthreads();
    for (int s = 64; s > 0; s >>= 1) {
        if (c < s) { r0[c] += r0[c + s]; r1[c] += r1[c + s]; }
        __syncthreads();
    }
    if (c == 0) {
        float s0 = r0[0] / (float)NTX, s1 = r1[0] / (float)NTX;
        float m = fmaxf(s0, s1);
        float e0 = expf(s0 - m), e1 = expf(s1 - m);
        float inv = 1.f / (e0 + e1);
        attn[0] = e0 * inv;
        attn[1] = e1 * inv;
    }
}

// ---------------------------------------------------------------------------
// final_pool: batch is SORTED -> group g is a contiguous run [lo,hi).
// 1024 threads = 8 row-slices x 128 channels; LDS tree over slices,
// then fused 128->2 linear.
// ---------------------------------------------------------------------------
__device__ __forceinline__ int lower_bound_g(const int* __restrict__ batch, int val)
{
    int lo = 0, hi = NTX;
    while (lo < hi) {
        int mid = (lo + hi) >> 1;
        if (batch[mid] < val) lo = mid + 1; else hi = mid;
    }
    return lo;
}

__global__ __launch_bounds__(1024) void final_pool_kernel(
    const f16* __restrict__ out_at, const f16* __restrict__ out_tt,
    const int* __restrict__ batch, const float* __restrict__ attn,
    const float* __restrict__ Wl, const float* __restrict__ bl,
    float* __restrict__ out)
{
    __shared__ float r0s[8][128], r1s[8][128];
    const int g = blockIdx.x;
    const int t = threadIdx.x;
    const int sub = t >> 7, c = t & 127;
    const int lo = lower_bound_g(batch, g);
    const int hi = lower_bound_g(batch, g + 1);
    float s0 = 0.f, s1 = 0.f;
    for (int n = lo + sub; n < hi; n += 8) {
        s0 += (float)out_at[(size_t)n * 128 + c];
        s1 += (float)out_tt[(size_t)n * 128 + c];
    }
    r0s[sub][c] = s0;
    r1s[sub][c] = s1;
    __syncthreads();
    for (int o = 4; o > 0; o >>= 1) {
        if (sub < o) {
            r0s[sub][c] += r0s[sub + o][c];
            r1s[sub][c] += r1s[sub + o][c];
        }
        __syncthreads();
    }
    if (t < 128) {
        float pooled = (attn[0] * r0s[0][t] + attn[1] * r1s[0][t])
                     / fmaxf((float)(hi - lo), 1.f);
        r0s[1][t] = pooled * Wl[t * 2 + 0];
        r1s[1][t] = pooled * Wl[t * 2 + 1];
    }
    __syncthreads();
    for (int s = 64; s > 0; s >>= 1) {
        if (t < s) { r0s[1][t] += r0s[1][t + s]; r1s[1][t] += r1s[1][t + s]; }
        __syncthreads();
    }
    if (t == 0) {
        out[g * 2 + 0] = r0s[1][0] + bl[0];
        out[g * 2 + 1] = r1s[1][0] + bl[1];
    }
}

// ---------------------------------------------------------------------------
extern "C" void kernel_launch(void* const* d_in, const int* in_sizes, int n_in,
                              void* d_out, int out_size, void* d_ws, size_t ws_size,
                              hipStream_t stream)
{
    const float* x_tx     = (const float*)d_in[0];
    const float* x_ad     = (const float*)d_in[1];
    // d_in[2] = ei_ta (dead: out_ta never consumed)
    const int*   ei_at    = (const int*)d_in[3];
    const int*   ei_tt    = (const int*)d_in[4];
    const int*   batch    = (const int*)d_in[5];
    const float* W_tx     = (const float*)d_in[6];
    const float* b_tx     = (const float*)d_in[7];
    const float* W_ad     = (const float*)d_in[8];
    const float* b_ad     = (const float*)d_in[9];
    // d_in[10], d_in[11] = a_src_ta, a_dst_ta (dead)
    const float* a_src_at = (const float*)d_in[12];
    const float* a_dst_at = (const float*)d_in[13];
    const float* a_src_tt = (const float*)d_in[14];
    const float* a_dst_tt = (const float*)d_in[15];
    const float* Wk       = (const float*)d_in[16];
    const float* bk       = (const float*)d_in[17];
    const float* q        = (const float*)d_in[18];
    const float* Wl       = (const float*)d_in[19];
    const float* bl       = (const float*)d_in[20];
    float* out = (float*)d_out;

    char* ws = (char*)d_ws;
    size_t off = 0;
    auto alloc = [&](size_t bytes) -> void* {
        void* p = ws + off;
        off += (bytes + 255) & ~(size_t)255;
        return p;
    };
    f16* h_tx      = (f16*)alloc((size_t)NTX * 128 * 2);
    f16* h_ad      = (f16*)alloc((size_t)NADDR * 128 * 2);
    f16* Wt_txg    = (f16*)alloc((size_t)128 * 128 * 2);   // pre-transposed fp16 weights
    f16* Wt_adg    = (f16*)alloc((size_t)128 * 128 * 2);
    f16* Wktg      = (f16*)alloc((size_t)128 * 128 * 2);
    float* al_sat  = (float*)alloc((size_t)NADDR * 4 * 4);
    float* al_dat  = (float*)alloc((size_t)NTX * 4 * 4);
    float* al_stt  = (float*)alloc((size_t)NTX * 4 * 4);
    float* al_dtt  = (float*)alloc((size_t)NTX * 4 * 4);
    f16* out_at    = (f16*)alloc((size_t)NTX * 128 * 2);   // fully written by gather
    f16* out_tt    = (f16*)alloc((size_t)NTX * 128 * 2);
    int* csr_at    = (int*)alloc((size_t)NE * 4);
    int* csr_tt    = (int*)alloc((size_t)NE * 4);
    int* rank_at   = (int*)alloc((size_t)NE * 4);
    int* rank_tt   = (int*)alloc((size_t)NE * 4);
    int* row_at    = (int*)alloc((size_t)NTX * 4);
    int* row_tt    = (int*)alloc((size_t)NTX * 4);
    int* csum      = (int*)alloc((size_t)2 * NCHUNK * 4);
    float* part    = (float*)alloc((size_t)2 * PBM * 128 * 4);
    // ---- zeroed region (counters / S accumulators) ----
    char* zero0 = ws + off;
    int* deg_at    = (int*)alloc((size_t)NTX * 4);
    int* deg_tt    = (int*)alloc((size_t)NTX * 4);
    float* S_at    = (float*)alloc(128 * 4);
    float* S_tt    = (float*)alloc(128 * 4);
    size_t zbytes = (size_t)((ws + off) - zero0);
    float* attnw   = (float*)alloc(2 * 4);

    hipMemsetAsync(zero0, 0, zbytes, stream);

    // one-shot fp16 weight transposes
    dim3 pgrid(4, 3);
    prep_kernel<<<pgrid, 256, 0, stream>>>(W_tx, W_ad, Wk, Wt_txg, Wt_adg, Wktg);

    // projections + attention-logit dots + FUSED degree/rank atomics
    proj2_kernel<<<2 * PBM, 256, 0, stream>>>(
        x_tx, Wt_txg, b_tx, h_tx, x_ad, Wt_adg, b_ad, h_ad,
        a_dst_at, al_dat, a_src_tt, al_stt, a_dst_tt, al_dtt,
        a_src_at, al_sat,
        ei_at, ei_tt, deg_at, deg_tt, rank_at, rank_tt);

    // CSR build rest (scan + rank-based fill, no atomics)
    dim3 sgrid(NCHUNK, 2);
    chunksum_kernel<<<sgrid, 256, 0, stream>>>(deg_at, deg_tt, csum);
    chunkscan_kernel<<<2, 256, 0, stream>>>(csum);
    scanwrite_kernel<<<sgrid, 256, 0, stream>>>(deg_at, deg_tt, csum, row_at, row_tt);
    int eb2 = (2 * NE + 255) / 256;
    fill2_kernel<<<eb2, 256, 0, stream>>>(
        ei_at, rank_at, row_at, csr_at,
        ei_tt, rank_tt, row_tt, csr_tt);

    // gather-style GAT: flat grid, 8-block tiles split types across XCD halves
    gat_gather2_kernel<<<PBM * 8, 256, 0, stream>>>(
        row_at, deg_at, csr_at, al_sat, al_dat, h_ad, out_at,
        row_tt, deg_tt, csr_tt, al_stt, al_dtt, h_tx, out_tt);

    // semantic attention: MFMA tanh GEMM (both metapaths/block) -> reduce -> softmax
    tanh_gemm_kernel<<<PBM, 256, 0, stream>>>(out_at, out_tt, Wktg, bk, part);
    dim3 rgrid(32, 2);
    reduceS_kernel<<<rgrid, 128, 0, stream>>>(part, S_at, S_tt);
    attn_kernel<<<1, 128, 0, stream>>>(S_at, S_tt, q, attnw);

    // fused pooling (sorted batch -> contiguous runs) + final linear
    final_pool_kernel<<<GG, 1024, 0, stream>>>(out_at, out_tt, batch, attnw, Wl, bl, out);
}